// Round 1
// baseline (2326.332 us; speedup 1.0000x reference)
//
#include <hip/hip_runtime.h>

// Problem constants (fixed by reference)
#define S_LEN 2048
#define D_DIM 1024
#define NH    16
#define HD    64
#define BATCH 4
#define M_ROWS (BATCH * S_LEN)  // 8192

// ---------------------------------------------------------------------------
// GEMM: C = A(8192x1024) * W(1024x1024)
// mode 0: C row-major [8192][1024]
// mode 1: C in head layout [B][H][S][HD]  (n-tile == one head since BN=64==HD)
// 64x64 tile, BK=32, 256 threads, 4x4 acc per thread.
// LDS stride 68: transposed-A stores are 2-way (free), inner reads are
// aligned ds_read_b128, conflict-free.
// ---------------------------------------------------------------------------
__global__ __launch_bounds__(256) void gemm_k(const float* __restrict__ A,
                                              const float* __restrict__ W,
                                              float* __restrict__ C, int mode)
{
    __shared__ float sA[32][68];   // [k][m] (A transposed)
    __shared__ float sB[32][68];   // [k][n]
    const int t  = threadIdx.x;
    const int tx = t & 15, ty = t >> 4;
    const int m0 = blockIdx.y * 64, n0 = blockIdx.x * 64;

    float acc[4][4] = {{0.f}};

    for (int k0 = 0; k0 < D_DIM; k0 += 32) {
        __syncthreads();
#pragma unroll
        for (int it = 0; it < 2; ++it) {
            int idx = t + it * 256;             // 0..511
            // A tile: 64 m x 32 k, float4 along k, scatter-transpose into sA
            int m = idx >> 3, kq = idx & 7;
            float4 va = *(const float4*)&A[(size_t)(m0 + m) * D_DIM + k0 + kq * 4];
            sA[kq * 4 + 0][m] = va.x;
            sA[kq * 4 + 1][m] = va.y;
            sA[kq * 4 + 2][m] = va.z;
            sA[kq * 4 + 3][m] = va.w;
            // B tile: 32 k x 64 n, float4 along n
            int kb = idx >> 4, nq = idx & 15;
            *(float4*)&sB[kb][nq * 4] =
                *(const float4*)&W[(size_t)(k0 + kb) * D_DIM + n0 + nq * 4];
        }
        __syncthreads();
#pragma unroll 8
        for (int kk = 0; kk < 32; ++kk) {
            float4 a4 = *(const float4*)&sA[kk][ty * 4];
            float4 b4 = *(const float4*)&sB[kk][tx * 4];
            float a[4] = {a4.x, a4.y, a4.z, a4.w};
            float b[4] = {b4.x, b4.y, b4.z, b4.w};
#pragma unroll
            for (int i = 0; i < 4; ++i)
#pragma unroll
                for (int j = 0; j < 4; ++j)
                    acc[i][j] += a[i] * b[j];
        }
    }

    if (mode == 0) {
#pragma unroll
        for (int i = 0; i < 4; ++i) {
            float4 st = {acc[i][0], acc[i][1], acc[i][2], acc[i][3]};
            *(float4*)&C[(size_t)(m0 + ty * 4 + i) * D_DIM + n0 + tx * 4] = st;
        }
    } else {
        const int h = n0 >> 6;
#pragma unroll
        for (int i = 0; i < 4; ++i) {
            int r = m0 + ty * 4 + i;
            int b = r >> 11;               // r / S_LEN
            int s = r & (S_LEN - 1);
            float4 st = {acc[i][0], acc[i][1], acc[i][2], acc[i][3]};
            *(float4*)&C[((size_t)(b * NH + h) * S_LEN + s) * HD + tx * 4] = st;
        }
    }
}

// ---------------------------------------------------------------------------
// Flash-style causal attention.
// grid: (S/64 q-tiles, B*H). 256 threads: tx=n-frag(16), ty=m-frag(16), 4x4.
// Q,K stored transposed [d][row] (stride 68 -> aligned b128, conflict-free).
// V stored direct [c][hd] (stride 64, 2-way max).
// P stays in registers; PV uses __shfl broadcast from fragment-owner lane.
// Online softmax state per row, replicated across the tx group.
// ---------------------------------------------------------------------------
__global__ __launch_bounds__(256) void attn_k(const float* __restrict__ Q,
                                              const float* __restrict__ Kp,
                                              const float* __restrict__ Vp,
                                              float* __restrict__ ctx)
{
    __shared__ float sQ[64][68];  // [d][r]
    __shared__ float sK[64][68];  // [d][c]
    __shared__ float sV[64][64];  // [c][hd]
    const int t  = threadIdx.x;
    const int tx = t & 15, ty = t >> 4;
    const int qt = blockIdx.x, bh = blockIdx.y;
    const int q0 = qt * 64;
    const float* Qb = Q  + (size_t)bh * S_LEN * HD;
    const float* Kb = Kp + (size_t)bh * S_LEN * HD;
    const float* Vb = Vp + (size_t)bh * S_LEN * HD;

    // Load Q tile transposed (once per block)
#pragma unroll
    for (int it = 0; it < 4; ++it) {
        int idx = t + it * 256;             // 0..1023
        int r = idx >> 4, dq = idx & 15;
        float4 v4 = *(const float4*)&Qb[(size_t)(q0 + r) * HD + dq * 4];
        sQ[dq * 4 + 0][r] = v4.x;
        sQ[dq * 4 + 1][r] = v4.y;
        sQ[dq * 4 + 2][r] = v4.z;
        sQ[dq * 4 + 3][r] = v4.w;
    }

    float o[4][4] = {{0.f}};
    float mrun[4], lrun[4];
#pragma unroll
    for (int i = 0; i < 4; ++i) { mrun[i] = -1e30f; lrun[i] = 0.f; }

    for (int kt = 0; kt <= qt; ++kt) {
        const int k0 = kt * 64;
        __syncthreads();   // previous PV done before overwriting sK/sV
#pragma unroll
        for (int it = 0; it < 4; ++it) {
            int idx = t + it * 256;
            int r = idx >> 4, dq = idx & 15;
            float4 kv = *(const float4*)&Kb[(size_t)(k0 + r) * HD + dq * 4];
            sK[dq * 4 + 0][r] = kv.x;
            sK[dq * 4 + 1][r] = kv.y;
            sK[dq * 4 + 2][r] = kv.z;
            sK[dq * 4 + 3][r] = kv.w;
            *(float4*)&sV[r][dq * 4] =
                *(const float4*)&Vb[(size_t)(k0 + r) * HD + dq * 4];
        }
        __syncthreads();

        // S = Q K^T  (4x4 fragment per thread)
        float s[4][4] = {{0.f}};
#pragma unroll 8
        for (int d = 0; d < 64; ++d) {
            float4 a4 = *(const float4*)&sQ[d][ty * 4];
            float4 b4 = *(const float4*)&sK[d][tx * 4];
            float a[4] = {a4.x, a4.y, a4.z, a4.w};
            float b[4] = {b4.x, b4.y, b4.z, b4.w};
#pragma unroll
            for (int i = 0; i < 4; ++i)
#pragma unroll
                for (int j = 0; j < 4; ++j)
                    s[i][j] += a[i] * b[j];
        }

        const bool diag = (kt == qt);
#pragma unroll
        for (int i = 0; i < 4; ++i) {
            const int r = ty * 4 + i;
#pragma unroll
            for (int j = 0; j < 4; ++j) {
                float val = s[i][j] * 0.125f;              // 1/sqrt(64)
                if (diag && (tx * 4 + j > r)) val = -1e30f; // causal mask
                s[i][j] = val;
            }
            // row max across the 16 tx lanes (xor<16 stays in tx group)
            float tm = fmaxf(fmaxf(s[i][0], s[i][1]), fmaxf(s[i][2], s[i][3]));
#pragma unroll
            for (int off = 1; off < 16; off <<= 1)
                tm = fmaxf(tm, __shfl_xor(tm, off, 64));
            float mnew  = fmaxf(mrun[i], tm);
            float alpha = __expf(mrun[i] - mnew);   // first tile: exp(-inf)=0
            mrun[i] = mnew;
            float rs = 0.f;
#pragma unroll
            for (int j = 0; j < 4; ++j) {
                s[i][j] = __expf(s[i][j] - mnew);   // masked -> exp(-1e30)=0
                rs += s[i][j];
            }
#pragma unroll
            for (int off = 1; off < 16; off <<= 1)
                rs += __shfl_xor(rs, off, 64);
            lrun[i] = lrun[i] * alpha + rs;
#pragma unroll
            for (int j = 0; j < 4; ++j) o[i][j] *= alpha;
        }

        // O += P * V ; P fragment broadcast via shuffle (owner lane base|cq)
        const int base = t & 48;
#pragma unroll 4
        for (int cq = 0; cq < 16; ++cq) {
#pragma unroll
            for (int jj = 0; jj < 4; ++jj) {
                const int c = cq * 4 + jj;
                float p0 = __shfl(s[0][jj], base + cq, 64);
                float p1 = __shfl(s[1][jj], base + cq, 64);
                float p2 = __shfl(s[2][jj], base + cq, 64);
                float p3 = __shfl(s[3][jj], base + cq, 64);
                float4 b4 = *(const float4*)&sV[c][tx * 4];
                float b[4] = {b4.x, b4.y, b4.z, b4.w};
#pragma unroll
                for (int j = 0; j < 4; ++j) {
                    o[0][j] += p0 * b[j];
                    o[1][j] += p1 * b[j];
                    o[2][j] += p2 * b[j];
                    o[3][j] += p3 * b[j];
                }
            }
        }
    }

    // finalize: divide by l, write ctx in [B][S][D] row-major
    const int b = bh >> 4, h = bh & 15;
#pragma unroll
    for (int i = 0; i < 4; ++i) {
        float inv = 1.f / lrun[i];
        float4 st = {o[i][0] * inv, o[i][1] * inv, o[i][2] * inv, o[i][3] * inv};
        *(float4*)&ctx[((size_t)(b * S_LEN) + q0 + ty * 4 + i) * D_DIM + h * HD + tx * 4] = st;
    }
}

extern "C" void kernel_launch(void* const* d_in, const int* in_sizes, int n_in,
                              void* d_out, int out_size, void* d_ws, size_t ws_size,
                              hipStream_t stream)
{
    const float* x  = (const float*)d_in[0];
    const float* wq = (const float*)d_in[1];
    const float* wk = (const float*)d_in[2];
    const float* wv = (const float*)d_in[3];
    const float* wo = (const float*)d_in[4];

    const size_t elems = (size_t)M_ROWS * D_DIM;   // 8388608
    float* q   = (float*)d_ws;
    float* k   = q + elems;
    float* v   = k + elems;
    float* ctx = v + elems;

    dim3 gg(D_DIM / 64, M_ROWS / 64);   // (16, 128)
    gemm_k<<<gg, 256, 0, stream>>>(x, wq, q, 1);
    gemm_k<<<gg, 256, 0, stream>>>(x, wk, k, 1);
    gemm_k<<<gg, 256, 0, stream>>>(x, wv, v, 1);

    attn_k<<<dim3(S_LEN / 64, BATCH * NH), 256, 0, stream>>>(q, k, v, ctx);

    gemm_k<<<gg, 256, 0, stream>>>(ctx, wo, (float*)d_out, 0);
}

// Round 2
// 544.563 us; speedup vs baseline: 4.2719x; 4.2719x over previous
//
#include <hip/hip_runtime.h>

#define S_LEN 2048
#define D_DIM 1024
#define NH    16
#define HD    64
#define BATCH 4
#define M_ROWS 8192

typedef __attribute__((ext_vector_type(8))) short bf16x8;   // 8 bf16 = 4 VGPR
typedef __attribute__((ext_vector_type(4))) float f32x4;
typedef __attribute__((ext_vector_type(8))) unsigned short u16x8;

__device__ __forceinline__ unsigned short f2bf(float f) {
    unsigned u = __builtin_bit_cast(unsigned, f);
    u = (u + 0x7fffu + ((u >> 16) & 1u)) >> 16;   // RNE truncate
    return (unsigned short)u;
}

__device__ __forceinline__ void gload16(const void* g, void* l) {
    __builtin_amdgcn_global_load_lds((const __attribute__((address_space(1))) unsigned*)g,
                                     (__attribute__((address_space(3))) unsigned*)l,
                                     16, 0, 0);
}

// ---------------------------------------------------------------------------
// x fp32 -> bf16 (row-major passthrough)
// ---------------------------------------------------------------------------
__global__ __launch_bounds__(256) void castx_k(const float* __restrict__ x,
                                               unsigned short* __restrict__ o) {
    size_t i = (size_t)blockIdx.x * 256 + threadIdx.x;   // 8 elems each
    const float4* xf = (const float4*)x;
    float4 a = xf[2 * i], b = xf[2 * i + 1];
    u16x8 v;
    v[0] = f2bf(a.x); v[1] = f2bf(a.y); v[2] = f2bf(a.z); v[3] = f2bf(a.w);
    v[4] = f2bf(b.x); v[5] = f2bf(b.y); v[6] = f2bf(b.z); v[7] = f2bf(b.w);
    *(u16x8*)(o + i * 8) = v;
}

// ---------------------------------------------------------------------------
// W fp32 [K][N] -> bf16 transposed [N][K]  (B^T layout for MFMA B-frags)
// ---------------------------------------------------------------------------
__global__ __launch_bounds__(256) void wprep_k(const float* __restrict__ w0, const float* __restrict__ w1,
                                               const float* __restrict__ w2, const float* __restrict__ w3,
                                               unsigned short* __restrict__ o0, unsigned short* __restrict__ o1,
                                               unsigned short* __restrict__ o2, unsigned short* __restrict__ o3) {
    __shared__ float sT[64][65];
    const float* w; unsigned short* o;
    switch (blockIdx.z) {
        case 0: w = w0; o = o0; break;
        case 1: w = w1; o = o1; break;
        case 2: w = w2; o = o2; break;
        default: w = w3; o = o3; break;
    }
    const int t = threadIdx.x;
    const int k0 = blockIdx.y * 64, n0 = blockIdx.x * 64;
    const int r = t >> 4, cq = t & 15;
#pragma unroll
    for (int it = 0; it < 4; ++it) {
        int k = r + it * 16;
        float4 v = *(const float4*)&w[(size_t)(k0 + k) * D_DIM + n0 + cq * 4];
        sT[k][cq * 4 + 0] = v.x; sT[k][cq * 4 + 1] = v.y;
        sT[k][cq * 4 + 2] = v.z; sT[k][cq * 4 + 3] = v.w;
    }
    __syncthreads();
    const int n = t >> 2, ch = t & 3;
    union { unsigned short s[8]; uint4 v; } p0, p1;
#pragma unroll
    for (int j = 0; j < 8; ++j) p0.s[j] = f2bf(sT[ch * 16 + j][n]);
#pragma unroll
    for (int j = 0; j < 8; ++j) p1.s[j] = f2bf(sT[ch * 16 + 8 + j][n]);
    *(uint4*)&o[(size_t)(n0 + n) * D_DIM + k0 + ch * 16]     = p0.v;
    *(uint4*)&o[(size_t)(n0 + n) * D_DIM + k0 + ch * 16 + 8] = p1.v;
}

// ---------------------------------------------------------------------------
// bf16 MFMA GEMM (m97 structure): C = A(8192x1024) * Bt^T, Bt is [N][K] bf16.
// 128x128 tile, BK=32, 4 waves in 2x2, 4x4 16x16x32 frags per wave.
// LDS rows 64B (4 x 16B chunks), chunk-rotation swizzle (g + m/2)&3 -> 2-way.
// outbf=1: bf16 row-major out; outbf=0: fp32 row-major out.
// ---------------------------------------------------------------------------
__global__ __launch_bounds__(256) void gemm_k(const unsigned short* __restrict__ A,
                                              const unsigned short* __restrict__ Bt,
                                              float* __restrict__ Cf,
                                              unsigned short* __restrict__ Cb,
                                              int outbf)
{
    __shared__ unsigned short sA[128 * 32];
    __shared__ unsigned short sB[128 * 32];
    const int t = threadIdx.x;
    const int lane = t & 63, w = t >> 6;
    const int mm = lane & 15, quad = lane >> 4;
    const int wm = w >> 1, wn = w & 1;
    const int m0 = blockIdx.y * 128, n0 = blockIdx.x * 128;

    f32x4 acc[4][4];
#pragma unroll
    for (int i = 0; i < 4; ++i)
#pragma unroll
        for (int j = 0; j < 4; ++j) acc[i][j] = (f32x4){0.f, 0.f, 0.f, 0.f};

    for (int k0 = 0; k0 < D_DIM; k0 += 32) {
        __syncthreads();
#pragma unroll
        for (int it = 0; it < 2; ++it) {
            int idx = t + it * 256;          // 0..511
            int m = idx >> 2, j = idx & 3;
            int g = (j - (m >> 1)) & 3;      // stored global chunk at slot j
            gload16(A  + ((size_t)(m0 + m) * D_DIM + k0 + g * 8), (void*)&sA[idx * 8]);
            gload16(Bt + ((size_t)(n0 + m) * D_DIM + k0 + g * 8), (void*)&sB[idx * 8]);
        }
        __syncthreads();

        bf16x8 af[4], bf[4];
#pragma unroll
        for (int mi = 0; mi < 4; ++mi) {
            int m = wm * 64 + mi * 16 + mm;
            int slot = (quad + (m >> 1)) & 3;
            af[mi] = *(const bf16x8*)&sA[m * 32 + slot * 8];
        }
#pragma unroll
        for (int ni = 0; ni < 4; ++ni) {
            int n = wn * 64 + ni * 16 + mm;
            int slot = (quad + (n >> 1)) & 3;
            bf[ni] = *(const bf16x8*)&sB[n * 32 + slot * 8];
        }
#pragma unroll
        for (int mi = 0; mi < 4; ++mi)
#pragma unroll
            for (int ni = 0; ni < 4; ++ni)
                acc[mi][ni] = __builtin_amdgcn_mfma_f32_16x16x32_bf16(af[mi], bf[ni], acc[mi][ni], 0, 0, 0);
    }

    // Epilogue: C-layout col = lane&15, row = quad*4 + reg
    if (outbf) {
#pragma unroll
        for (int mi = 0; mi < 4; ++mi)
#pragma unroll
            for (int ni = 0; ni < 4; ++ni)
#pragma unroll
                for (int r = 0; r < 4; ++r)
                    Cb[(size_t)(m0 + wm * 64 + mi * 16 + quad * 4 + r) * D_DIM +
                       n0 + wn * 64 + ni * 16 + mm] = f2bf(acc[mi][ni][r]);
    } else {
#pragma unroll
        for (int mi = 0; mi < 4; ++mi)
#pragma unroll
            for (int ni = 0; ni < 4; ++ni)
#pragma unroll
                for (int r = 0; r < 4; ++r)
                    Cf[(size_t)(m0 + wm * 64 + mi * 16 + quad * 4 + r) * D_DIM +
                       n0 + wn * 64 + ni * 16 + mm] = acc[mi][ni][r];
    }
}

// ---------------------------------------------------------------------------
// Fused causal flash attention, bf16 MFMA.
// Q,K,V,ctx are bf16 row-major [B*S][D]; head h occupies cols h*64..h*64+63.
// Per block: 128 q-rows, 4 waves (32 q-rows each). K-tiles of 64.
// S^T = K*Q^T  (C cols = q-rows) so P packs into sP[m][c] with b64 writes and
// reads back as PV A-frags with b128 — no cross-wave traffic on sP.
// All LDS rows are 128B with chunk-XOR swizzle -> <=2-way (free) everywhere.
// ---------------------------------------------------------------------------
__global__ __launch_bounds__(256) void attn_k(const unsigned short* __restrict__ Q,
                                              const unsigned short* __restrict__ K,
                                              const unsigned short* __restrict__ V,
                                              unsigned short* __restrict__ ctx)
{
    __shared__ unsigned short sK [64 * 64];   // [key][hd]  8KB
    __shared__ unsigned short sVT[64 * 64];   // [hd][key]  8KB
    __shared__ unsigned short sP [128 * 64];  // [qrow][key] 16KB

    const int t = threadIdx.x;
    const int lane = t & 63, w = t >> 6;
    const int mm = lane & 15, quad = lane >> 4;
    const int qt = (int)gridDim.x - 1 - (int)blockIdx.x;   // heavy blocks first
    const int bh = blockIdx.y;
    const int b = bh >> 4, hh = bh & 15;
    const int q0 = qt * 128;
    const size_t rowbase = (size_t)b * S_LEN;
    const int coff = hh * HD;
    const float SCALE = 0.125f * 1.44269504088896341f;     // 1/sqrt(64) * log2(e)

    // Q fragments in registers (B-operand of S^T): [qrow][hd-chunk]
    bf16x8 qf[2][2];
#pragma unroll
    for (int f = 0; f < 2; ++f)
#pragma unroll
        for (int kk = 0; kk < 2; ++kk)
            qf[f][kk] = *(const bf16x8*)(Q + ((rowbase + q0 + w * 32 + f * 16 + mm) * D_DIM
                                              + coff + kk * 32 + quad * 8));

    f32x4 o[2][4];
#pragma unroll
    for (int f = 0; f < 2; ++f)
#pragma unroll
        for (int hf = 0; hf < 4; ++hf) o[f][hf] = (f32x4){0.f, 0.f, 0.f, 0.f};
    float mrow[2] = {-1e30f, -1e30f}, lrow[2] = {0.f, 0.f};

    const int nkt = 2 * qt + 2;
    for (int kt = 0; kt < nkt; ++kt) {
        const int k0 = kt * 64;
        __syncthreads();                       // protect sK/sVT reuse
        // Stage K tile via global_load_lds (lane-linear LDS, swizzled source)
#pragma unroll
        for (int it = 0; it < 2; ++it) {
            int idx = t + it * 256;            // 0..511
            int c = idx >> 3, j = idx & 7;
            int g = j ^ (c & 7);
            gload16(K + ((rowbase + k0 + c) * D_DIM + coff + g * 8), (void*)&sK[idx * 8]);
        }
        // Stage V transposed (scalar LDS writes, 2-way by swizzle)
#pragma unroll
        for (int it = 0; it < 2; ++it) {
            int c = lane, hd0 = w * 8 + it * 32;
            union { uint4 u; unsigned short s[8]; } vv;
            vv.u = *(const uint4*)(V + ((rowbase + k0 + c) * D_DIM + coff + hd0));
#pragma unroll
            for (int j = 0; j < 8; ++j) {
                int hd = hd0 + j;
                sVT[hd * 64 + (((c >> 3) ^ (hd & 7)) * 8) + (c & 7)] = vv.s[j];
            }
        }
        __syncthreads();

        // S^T = K * Q^T : frag (kf over keys, nf over qrows)
        f32x4 sacc[4][2];
#pragma unroll
        for (int kf = 0; kf < 4; ++kf)
#pragma unroll
            for (int nf = 0; nf < 2; ++nf) sacc[kf][nf] = (f32x4){0.f, 0.f, 0.f, 0.f};
#pragma unroll
        for (int kk = 0; kk < 2; ++kk) {
            bf16x8 ak[4];
#pragma unroll
            for (int kf = 0; kf < 4; ++kf) {
                int key = kf * 16 + mm;
                int slot = (kk * 4 + quad) ^ (key & 7);
                ak[kf] = *(const bf16x8*)&sK[key * 64 + slot * 8];
            }
#pragma unroll
            for (int kf = 0; kf < 4; ++kf)
#pragma unroll
                for (int nf = 0; nf < 2; ++nf)
                    sacc[kf][nf] = __builtin_amdgcn_mfma_f32_16x16x32_bf16(ak[kf], qf[nf][kk], sacc[kf][nf], 0, 0, 0);
        }

        // Online softmax in S^T layout: lane holds 16 keys per q-row, 2 q-rows
        const bool needmask = (k0 + 63) > (q0 + w * 32);
        float alpha[2];
#pragma unroll
        for (int nf = 0; nf < 2; ++nf) {
            const int qr = q0 + w * 32 + nf * 16 + mm;
            float tmax = -1e30f;
#pragma unroll
            for (int kf = 0; kf < 4; ++kf)
#pragma unroll
                for (int r = 0; r < 4; ++r) {
                    float v = sacc[kf][nf][r] * SCALE;
                    if (needmask && (k0 + kf * 16 + quad * 4 + r) > qr) v = -1e30f;
                    sacc[kf][nf][r] = v;
                    tmax = fmaxf(tmax, v);
                }
            tmax = fmaxf(tmax, __shfl_xor(tmax, 16, 64));
            tmax = fmaxf(tmax, __shfl_xor(tmax, 32, 64));
            float mnew = fmaxf(mrow[nf], tmax);
            alpha[nf] = exp2f(mrow[nf] - mnew);
            mrow[nf] = mnew;
            float rs = 0.f;
#pragma unroll
            for (int kf = 0; kf < 4; ++kf)
#pragma unroll
                for (int r = 0; r < 4; ++r) {
                    float p = exp2f(sacc[kf][nf][r] - mnew);
                    sacc[kf][nf][r] = p;
                    rs += p;
                }
            rs += __shfl_xor(rs, 16, 64);
            rs += __shfl_xor(rs, 32, 64);
            lrow[nf] = lrow[nf] * alpha[nf] + rs;
        }

        // Write P to sP (b64, 4 contiguous keys per lane; swizzled chunk-16B)
#pragma unroll
        for (int nf = 0; nf < 2; ++nf) {
            int m = w * 32 + nf * 16 + mm;
#pragma unroll
            for (int kf = 0; kf < 4; ++kf) {
                union { unsigned short s[4]; unsigned long long ll; } pk;
                pk.s[0] = f2bf(sacc[kf][nf][0]); pk.s[1] = f2bf(sacc[kf][nf][1]);
                pk.s[2] = f2bf(sacc[kf][nf][2]); pk.s[3] = f2bf(sacc[kf][nf][3]);
                int slot = (kf * 2 + (quad >> 1)) ^ (m & 7);
                *(unsigned long long*)&sP[m * 64 + slot * 8 + (quad & 1) * 4] = pk.ll;
            }
        }
        // no barrier: each wave reads only its own 32 sP rows

        // Rescale O by alpha (broadcast to O-row layout)
#pragma unroll
        for (int f = 0; f < 2; ++f)
#pragma unroll
            for (int r = 0; r < 4; ++r) {
                float a = __shfl(alpha[f], (lane & 48) | (quad * 4 + r), 64);
#pragma unroll
                for (int hf = 0; hf < 4; ++hf) o[f][hf][r] *= a;
            }

        // O += P * V   (A = sP rows, B = sVT rows)
#pragma unroll
        for (int kk = 0; kk < 2; ++kk) {
            bf16x8 pf[2], vf[4];
#pragma unroll
            for (int f = 0; f < 2; ++f) {
                int m = w * 32 + f * 16 + mm;
                int slot = (kk * 4 + quad) ^ (m & 7);
                pf[f] = *(const bf16x8*)&sP[m * 64 + slot * 8];
            }
#pragma unroll
            for (int hf = 0; hf < 4; ++hf) {
                int hd = hf * 16 + mm;
                int slot = (kk * 4 + quad) ^ (hd & 7);
                vf[hf] = *(const bf16x8*)&sVT[hd * 64 + slot * 8];
            }
#pragma unroll
            for (int f = 0; f < 2; ++f)
#pragma unroll
                for (int hf = 0; hf < 4; ++hf)
                    o[f][hf] = __builtin_amdgcn_mfma_f32_16x16x32_bf16(pf[f], vf[hf], o[f][hf], 0, 0, 0);
        }
    }

    // Normalize by l and store ctx (bf16 row-major)
#pragma unroll
    for (int f = 0; f < 2; ++f)
#pragma unroll
        for (int r = 0; r < 4; ++r) {
            float lv = __shfl(lrow[f], (lane & 48) | (quad * 4 + r), 64);
            float inv = 1.f / lv;
            int row = q0 + w * 32 + f * 16 + quad * 4 + r;
#pragma unroll
            for (int hf = 0; hf < 4; ++hf)
                ctx[(rowbase + row) * D_DIM + coff + hf * 16 + mm] = f2bf(o[f][hf][r] * inv);
        }
}

extern "C" void kernel_launch(void* const* d_in, const int* in_sizes, int n_in,
                              void* d_out, int out_size, void* d_ws, size_t ws_size,
                              hipStream_t stream)
{
    const float* x  = (const float*)d_in[0];
    const float* wq = (const float*)d_in[1];
    const float* wk = (const float*)d_in[2];
    const float* wv = (const float*)d_in[3];
    const float* wo = (const float*)d_in[4];

    const size_t XE = (size_t)M_ROWS * D_DIM;   // 8M elems
    const size_t WE = (size_t)D_DIM * D_DIM;    // 1M elems
    unsigned short* ws  = (unsigned short*)d_ws;
    unsigned short* xbf = ws;
    unsigned short* wt0 = xbf + XE;
    unsigned short* wt1 = wt0 + WE;
    unsigned short* wt2 = wt1 + WE;
    unsigned short* wt3 = wt2 + WE;
    unsigned short* qb  = wt3 + WE;
    unsigned short* kb  = qb + XE;
    unsigned short* vb  = kb + XE;
    unsigned short* cb  = vb + XE;               // total 88 MB

    castx_k<<<dim3(M_ROWS * D_DIM / (256 * 8)), 256, 0, stream>>>(x, xbf);
    wprep_k<<<dim3(16, 16, 4), 256, 0, stream>>>(wq, wk, wv, wo, wt0, wt1, wt2, wt3);

    dim3 gg(D_DIM / 128, M_ROWS / 128);          // (8, 64)
    gemm_k<<<gg, 256, 0, stream>>>(xbf, wt0, nullptr, qb, 1);
    gemm_k<<<gg, 256, 0, stream>>>(xbf, wt1, nullptr, kb, 1);
    gemm_k<<<gg, 256, 0, stream>>>(xbf, wt2, nullptr, vb, 1);

    attn_k<<<dim3(S_LEN / 128, BATCH * NH), 256, 0, stream>>>(qb, kb, vb, cb);

    gemm_k<<<gg, 256, 0, stream>>>(cb, wt3, (float*)d_out, nullptr, 0);
}

// Round 3
// 332.338 us; speedup vs baseline: 6.9999x; 1.6386x over previous
//
#include <hip/hip_runtime.h>

#define S_LEN 2048
#define D_DIM 1024
#define NH    16
#define HD    64
#define BATCH 4
#define M_ROWS 8192

typedef __attribute__((ext_vector_type(8))) short bf16x8;   // 8 bf16 = 4 VGPR
typedef __attribute__((ext_vector_type(4))) float f32x4;
typedef __attribute__((ext_vector_type(8))) unsigned short u16x8;

__device__ __forceinline__ unsigned short f2bf(float f) {
    unsigned u = __builtin_bit_cast(unsigned, f);
    u = (u + 0x7fffu + ((u >> 16) & 1u)) >> 16;   // RNE
    return (unsigned short)u;
}
// cheap round-half-up pack of two f32 -> packed bf16x2 (bias cancels via l-from-same-P)
__device__ __forceinline__ unsigned pack2(float a, float b) {
    unsigned ua = __builtin_bit_cast(unsigned, a);
    unsigned ub = __builtin_bit_cast(unsigned, b);
    return ((ua + 0x8000u) >> 16) | ((ub + 0x8000u) & 0xffff0000u);
}

__device__ __forceinline__ void gload16(const void* g, void* l) {
    __builtin_amdgcn_global_load_lds((const __attribute__((address_space(1))) unsigned*)g,
                                     (__attribute__((address_space(3))) unsigned*)l,
                                     16, 0, 0);
}

// ---------------------------------------------------------------------------
// x fp32 -> bf16
// ---------------------------------------------------------------------------
__global__ __launch_bounds__(256) void castx_k(const float* __restrict__ x,
                                               unsigned short* __restrict__ o) {
    size_t i = (size_t)blockIdx.x * 256 + threadIdx.x;
    const float4* xf = (const float4*)x;
    float4 a = xf[2 * i], b = xf[2 * i + 1];
    u16x8 v;
    v[0] = f2bf(a.x); v[1] = f2bf(a.y); v[2] = f2bf(a.z); v[3] = f2bf(a.w);
    v[4] = f2bf(b.x); v[5] = f2bf(b.y); v[6] = f2bf(b.z); v[7] = f2bf(b.w);
    *(u16x8*)(o + i * 8) = v;
}

// ---------------------------------------------------------------------------
// W fp32 [K][N] -> bf16 transposed [N][K]; wq additionally pre-scaled by
// softmax scale (1/sqrt(64) * log2(e)) so attention needs no per-elem mul.
// ---------------------------------------------------------------------------
__global__ __launch_bounds__(256) void wprep_k(const float* __restrict__ w0, const float* __restrict__ w1,
                                               const float* __restrict__ w2, const float* __restrict__ w3,
                                               unsigned short* __restrict__ o0, unsigned short* __restrict__ o1,
                                               unsigned short* __restrict__ o2, unsigned short* __restrict__ o3) {
    __shared__ float sT[64][65];
    const float* w; unsigned short* o;
    switch (blockIdx.z) {
        case 0: w = w0; o = o0; break;
        case 1: w = w1; o = o1; break;
        case 2: w = w2; o = o2; break;
        default: w = w3; o = o3; break;
    }
    const float sc = (blockIdx.z == 0) ? 0.18033688011112042f : 1.0f;  // 0.125*log2e
    const int t = threadIdx.x;
    const int k0 = blockIdx.y * 64, n0 = blockIdx.x * 64;
    const int r = t >> 4, cq = t & 15;
#pragma unroll
    for (int it = 0; it < 4; ++it) {
        int k = r + it * 16;
        float4 v = *(const float4*)&w[(size_t)(k0 + k) * D_DIM + n0 + cq * 4];
        sT[k][cq * 4 + 0] = v.x; sT[k][cq * 4 + 1] = v.y;
        sT[k][cq * 4 + 2] = v.z; sT[k][cq * 4 + 3] = v.w;
    }
    __syncthreads();
    const int n = t >> 2, ch = t & 3;
    union { unsigned short s[8]; uint4 v; } p0, p1;
#pragma unroll
    for (int j = 0; j < 8; ++j) p0.s[j] = f2bf(sT[ch * 16 + j][n] * sc);
#pragma unroll
    for (int j = 0; j < 8; ++j) p1.s[j] = f2bf(sT[ch * 16 + 8 + j][n] * sc);
    *(uint4*)&o[(size_t)(n0 + n) * D_DIM + k0 + ch * 16]     = p0.v;
    *(uint4*)&o[(size_t)(n0 + n) * D_DIM + k0 + ch * 16 + 8] = p1.v;
}

// ---------------------------------------------------------------------------
// Fused QKV GEMM: C = x(8192x1024) * [WqT|WkT|WvT]^T (N=3072), bf16 out into
// three row-major [8192][1024] buffers (widx = n0>>10). m97 structure.
// ---------------------------------------------------------------------------
__global__ __launch_bounds__(256) void gemmqkv_k(const unsigned short* __restrict__ A,
                                                 const unsigned short* __restrict__ Bt,
                                                 unsigned short* __restrict__ qkv)
{
    __shared__ unsigned short sA[128 * 32];
    __shared__ unsigned short sB[128 * 32];
    const int t = threadIdx.x;
    const int lane = t & 63, w = t >> 6;
    const int mm = lane & 15, quad = lane >> 4;
    const int wm = w >> 1, wn = w & 1;
    const int m0 = blockIdx.y * 128, n0 = blockIdx.x * 128;

    f32x4 acc[4][4];
#pragma unroll
    for (int i = 0; i < 4; ++i)
#pragma unroll
        for (int j = 0; j < 4; ++j) acc[i][j] = (f32x4){0.f, 0.f, 0.f, 0.f};

    for (int k0 = 0; k0 < D_DIM; k0 += 32) {
        __syncthreads();
#pragma unroll
        for (int it = 0; it < 2; ++it) {
            int idx = t + it * 256;
            int m = idx >> 2, j = idx & 3;
            int g = (j - (m >> 1)) & 3;
            gload16(A  + ((size_t)(m0 + m) * D_DIM + k0 + g * 8), (void*)&sA[idx * 8]);
            gload16(Bt + ((size_t)(n0 + m) * D_DIM + k0 + g * 8), (void*)&sB[idx * 8]);
        }
        __syncthreads();

        bf16x8 af[4], bfr[4];
#pragma unroll
        for (int mi = 0; mi < 4; ++mi) {
            int m = wm * 64 + mi * 16 + mm;
            int slot = (quad + (m >> 1)) & 3;
            af[mi] = *(const bf16x8*)&sA[m * 32 + slot * 8];
        }
#pragma unroll
        for (int ni = 0; ni < 4; ++ni) {
            int n = wn * 64 + ni * 16 + mm;
            int slot = (quad + (n >> 1)) & 3;
            bfr[ni] = *(const bf16x8*)&sB[n * 32 + slot * 8];
        }
#pragma unroll
        for (int mi = 0; mi < 4; ++mi)
#pragma unroll
            for (int ni = 0; ni < 4; ++ni)
                acc[mi][ni] = __builtin_amdgcn_mfma_f32_16x16x32_bf16(af[mi], bfr[ni], acc[mi][ni], 0, 0, 0);
    }

    const int widx = n0 >> 10;
    const int nl0  = n0 & 1023;
    unsigned short* outp = qkv + (size_t)widx * ((size_t)M_ROWS * D_DIM);
#pragma unroll
    for (int mi = 0; mi < 4; ++mi)
#pragma unroll
        for (int ni = 0; ni < 4; ++ni)
#pragma unroll
            for (int r = 0; r < 4; ++r)
                outp[(size_t)(m0 + wm * 64 + mi * 16 + quad * 4 + r) * D_DIM +
                     nl0 + wn * 64 + ni * 16 + mm] = f2bf(acc[mi][ni][r]);
}

// ---------------------------------------------------------------------------
// Output GEMM: out_fp32 = ctx_bf16 * WoT^T
// ---------------------------------------------------------------------------
__global__ __launch_bounds__(256) void gemmo_k(const unsigned short* __restrict__ A,
                                               const unsigned short* __restrict__ Bt,
                                               float* __restrict__ C)
{
    __shared__ unsigned short sA[128 * 32];
    __shared__ unsigned short sB[128 * 32];
    const int t = threadIdx.x;
    const int lane = t & 63, w = t >> 6;
    const int mm = lane & 15, quad = lane >> 4;
    const int wm = w >> 1, wn = w & 1;
    const int m0 = blockIdx.y * 128, n0 = blockIdx.x * 128;

    f32x4 acc[4][4];
#pragma unroll
    for (int i = 0; i < 4; ++i)
#pragma unroll
        for (int j = 0; j < 4; ++j) acc[i][j] = (f32x4){0.f, 0.f, 0.f, 0.f};

    for (int k0 = 0; k0 < D_DIM; k0 += 32) {
        __syncthreads();
#pragma unroll
        for (int it = 0; it < 2; ++it) {
            int idx = t + it * 256;
            int m = idx >> 2, j = idx & 3;
            int g = (j - (m >> 1)) & 3;
            gload16(A  + ((size_t)(m0 + m) * D_DIM + k0 + g * 8), (void*)&sA[idx * 8]);
            gload16(Bt + ((size_t)(n0 + m) * D_DIM + k0 + g * 8), (void*)&sB[idx * 8]);
        }
        __syncthreads();

        bf16x8 af[4], bfr[4];
#pragma unroll
        for (int mi = 0; mi < 4; ++mi) {
            int m = wm * 64 + mi * 16 + mm;
            int slot = (quad + (m >> 1)) & 3;
            af[mi] = *(const bf16x8*)&sA[m * 32 + slot * 8];
        }
#pragma unroll
        for (int ni = 0; ni < 4; ++ni) {
            int n = wn * 64 + ni * 16 + mm;
            int slot = (quad + (n >> 1)) & 3;
            bfr[ni] = *(const bf16x8*)&sB[n * 32 + slot * 8];
        }
#pragma unroll
        for (int mi = 0; mi < 4; ++mi)
#pragma unroll
            for (int ni = 0; ni < 4; ++ni)
                acc[mi][ni] = __builtin_amdgcn_mfma_f32_16x16x32_bf16(af[mi], bfr[ni], acc[mi][ni], 0, 0, 0);
    }
#pragma unroll
    for (int mi = 0; mi < 4; ++mi)
#pragma unroll
        for (int ni = 0; ni < 4; ++ni)
#pragma unroll
            for (int r = 0; r < 4; ++r)
                C[(size_t)(m0 + wm * 64 + mi * 16 + quad * 4 + r) * D_DIM +
                  n0 + wn * 64 + ni * 16 + mm] = acc[mi][ni][r];
}

// ---------------------------------------------------------------------------
// V row-major [8192][1024] -> V^T per head: vt[bh][hd][s]  (64x64 LDS tiles)
// ---------------------------------------------------------------------------
__global__ __launch_bounds__(256) void vtrans_k(const unsigned short* __restrict__ vb,
                                                unsigned short* __restrict__ vt)
{
    __shared__ unsigned short sT[64][72];
    const int t = threadIdx.x;
    const int st0 = blockIdx.x * 64, bh = blockIdx.y;
    const int b = bh >> 4, hh = bh & 15;
#pragma unroll
    for (int it = 0; it < 2; ++it) {
        int idx = t + it * 256;
        int r = idx >> 3, j = idx & 7;
        u16x8 v = *(const u16x8*)&vb[(size_t)(b * S_LEN + st0 + r) * D_DIM + hh * 64 + j * 8];
#pragma unroll
        for (int e = 0; e < 8; ++e) sT[j * 8 + e][r] = v[e];
    }
    __syncthreads();
#pragma unroll
    for (int it = 0; it < 2; ++it) {
        int idx = t + it * 256;
        int hd = idx >> 3, j = idx & 7;
        u16x8 ov = *(const u16x8*)&sT[hd][j * 8];
        *(u16x8*)&vt[((size_t)bh * HD + hd) * S_LEN + st0 + j * 8] = ov;
    }
}

// ---------------------------------------------------------------------------
// Fused causal flash attention, bf16 MFMA, fixed-max softmax.
// Each block handles TWO q-strips {qt, 15-qt} -> uniform 34 k-tiles/block.
// l computed via MFMA against all-ones B (same bf16 P as PV -> bias cancels,
// zero cross-lane reductions). K and V^T staged with global_load_lds.
// ---------------------------------------------------------------------------
__global__ __launch_bounds__(256, 4) void attn_k(const unsigned short* __restrict__ Q,
                                                 const unsigned short* __restrict__ K,
                                                 const unsigned short* __restrict__ Vt,
                                                 unsigned short* __restrict__ ctx)
{
    __shared__ unsigned short sK [64 * 64];   // [key][hd]   8KB
    __shared__ unsigned short sVT[64 * 64];   // [hd][key]   8KB
    __shared__ unsigned short sP [128 * 64];  // [qrow][key] 16KB
    const int t = threadIdx.x;
    const int lane = t & 63, w = t >> 6;
    const int mm = lane & 15, quad = lane >> 4;
    const int pair = blockIdx.x, bh = blockIdx.y;
    const int b = bh >> 4, hh = bh & 15;
    const size_t rowbase = (size_t)b * S_LEN;
    const int coff = hh * HD;
    const unsigned short* Vh = Vt + (size_t)bh * HD * S_LEN;

    u16x8 onesu;
#pragma unroll
    for (int j = 0; j < 8; ++j) onesu[j] = 0x3F80;   // bf16 1.0
    const bf16x8 ones = __builtin_bit_cast(bf16x8, onesu);

    for (int sidx = 0; sidx < 2; ++sidx) {
        const int qt = sidx ? (15 - pair) : pair;
        const int q0 = qt * 128;

        bf16x8 qf[2][2];
#pragma unroll
        for (int f = 0; f < 2; ++f)
#pragma unroll
            for (int kk = 0; kk < 2; ++kk)
                qf[f][kk] = *(const bf16x8*)(Q + (rowbase + q0 + w * 32 + f * 16 + mm) * D_DIM
                                               + coff + kk * 32 + quad * 8);
        f32x4 o[2][4], lacc[2];
#pragma unroll
        for (int f = 0; f < 2; ++f) {
            lacc[f] = (f32x4){0.f, 0.f, 0.f, 0.f};
#pragma unroll
            for (int hf = 0; hf < 4; ++hf) o[f][hf] = (f32x4){0.f, 0.f, 0.f, 0.f};
        }

        const int nkt = 2 * qt + 2;
        const int qrmax = q0 + w * 32 + 31;
        for (int kt = 0; kt < nkt; ++kt) {
            const int k0 = kt * 64;
            __syncthreads();
#pragma unroll
            for (int it = 0; it < 2; ++it) {
                int idx = t + it * 256;
                int c = idx >> 3, j = idx & 7, g = j ^ (c & 7);
                gload16(K  + (rowbase + k0 + c) * D_DIM + coff + g * 8, (void*)&sK[idx * 8]);
                gload16(Vh + (size_t)c * S_LEN + k0 + g * 8,            (void*)&sVT[idx * 8]);
            }
            __syncthreads();
            if (k0 > qrmax) continue;   // fully masked for this wave (barriers stay uniform)

            // S = Q K^T computed transposed: A=K rows, B=Q rows
            f32x4 sacc[4][2];
#pragma unroll
            for (int kf = 0; kf < 4; ++kf)
#pragma unroll
                for (int nf = 0; nf < 2; ++nf) sacc[kf][nf] = (f32x4){0.f, 0.f, 0.f, 0.f};
#pragma unroll
            for (int kk = 0; kk < 2; ++kk) {
                bf16x8 ak[4];
#pragma unroll
                for (int kf = 0; kf < 4; ++kf) {
                    int key = kf * 16 + mm;
                    int slot = (kk * 4 + quad) ^ (key & 7);
                    ak[kf] = *(const bf16x8*)&sK[key * 64 + slot * 8];
                }
#pragma unroll
                for (int kf = 0; kf < 4; ++kf)
#pragma unroll
                    for (int nf = 0; nf < 2; ++nf)
                        sacc[kf][nf] = __builtin_amdgcn_mfma_f32_16x16x32_bf16(ak[kf], qf[nf][kk], sacc[kf][nf], 0, 0, 0);
            }

            // p = exp2(s) (scale folded into wq), mask -> 0, pack to sP
            const bool needmask = (k0 + 63) > (q0 + w * 32);
#pragma unroll
            for (int nf = 0; nf < 2; ++nf) {
                const int qr = q0 + w * 32 + nf * 16 + mm;
                const int m = w * 32 + nf * 16 + mm;
#pragma unroll
                for (int kf = 0; kf < 4; ++kf) {
                    float p[4];
#pragma unroll
                    for (int r = 0; r < 4; ++r) {
                        p[r] = __builtin_amdgcn_exp2f(sacc[kf][nf][r]);
                        if (needmask && (k0 + kf * 16 + quad * 4 + r) > qr) p[r] = 0.f;
                    }
                    unsigned lo = pack2(p[0], p[1]), hi = pack2(p[2], p[3]);
                    int slot = (kf * 2 + (quad >> 1)) ^ (m & 7);
                    *(unsigned long long*)&sP[m * 64 + slot * 8 + (quad & 1) * 4] =
                        ((unsigned long long)hi << 32) | lo;
                }
            }
            // no barrier: sP rows are wave-private

            // O += P V ; l += P * ones
#pragma unroll
            for (int kk = 0; kk < 2; ++kk) {
                bf16x8 pf[2], vf[4];
#pragma unroll
                for (int f = 0; f < 2; ++f) {
                    int m = w * 32 + f * 16 + mm;
                    int slot = (kk * 4 + quad) ^ (m & 7);
                    pf[f] = *(const bf16x8*)&sP[m * 64 + slot * 8];
                }
#pragma unroll
                for (int hf = 0; hf < 4; ++hf) {
                    int hd = hf * 16 + mm;
                    int slot = (kk * 4 + quad) ^ (hd & 7);
                    vf[hf] = *(const bf16x8*)&sVT[hd * 64 + slot * 8];
                }
#pragma unroll
                for (int f = 0; f < 2; ++f) {
                    lacc[f] = __builtin_amdgcn_mfma_f32_16x16x32_bf16(pf[f], ones, lacc[f], 0, 0, 0);
#pragma unroll
                    for (int hf = 0; hf < 4; ++hf)
                        o[f][hf] = __builtin_amdgcn_mfma_f32_16x16x32_bf16(pf[f], vf[hf], o[f][hf], 0, 0, 0);
                }
            }
        }

        // normalize (l is in matching C-layout regs -> no shuffles) and store
#pragma unroll
        for (int f = 0; f < 2; ++f)
#pragma unroll
            for (int r = 0; r < 4; ++r) {
                float inv = 1.f / lacc[f][r];
                int row = q0 + w * 32 + f * 16 + quad * 4 + r;
#pragma unroll
                for (int hf = 0; hf < 4; ++hf)
                    ctx[(rowbase + row) * D_DIM + coff + hf * 16 + mm] = f2bf(o[f][hf][r] * inv);
            }
        __syncthreads();   // strip A's last PV reads done before strip B restages
    }
}

extern "C" void kernel_launch(void* const* d_in, const int* in_sizes, int n_in,
                              void* d_out, int out_size, void* d_ws, size_t ws_size,
                              hipStream_t stream)
{
    const float* x  = (const float*)d_in[0];
    const float* wq = (const float*)d_in[1];
    const float* wk = (const float*)d_in[2];
    const float* wv = (const float*)d_in[3];
    const float* wo = (const float*)d_in[4];

    const size_t XE = (size_t)M_ROWS * D_DIM;   // 8M elems
    const size_t WE = (size_t)D_DIM * D_DIM;    // 1M elems
    unsigned short* ws  = (unsigned short*)d_ws;
    unsigned short* xbf = ws;
    unsigned short* wt0 = xbf + XE;
    unsigned short* wt1 = wt0 + WE;
    unsigned short* wt2 = wt1 + WE;
    unsigned short* wt3 = wt2 + WE;
    unsigned short* qb  = wt3 + WE;     // q,k,v contiguous (fused epilogue)
    unsigned short* kb  = qb + XE;
    unsigned short* vb  = kb + XE;
    unsigned short* vt  = vb + XE;
    unsigned short* cb  = vt + XE;      // ~109 MB total

    castx_k<<<dim3(M_ROWS * D_DIM / (256 * 8)), 256, 0, stream>>>(x, xbf);
    wprep_k<<<dim3(16, 16, 4), 256, 0, stream>>>(wq, wk, wv, wo, wt0, wt1, wt2, wt3);

    gemmqkv_k<<<dim3(3 * D_DIM / 128, M_ROWS / 128), 256, 0, stream>>>(xbf, wt0, qb);
    vtrans_k<<<dim3(S_LEN / 64, BATCH * NH), 256, 0, stream>>>(vb, vt);

    attn_k<<<dim3(8, BATCH * NH), 256, 0, stream>>>(qb, kb, vt, cb);

    gemmo_k<<<dim3(D_DIM / 128, M_ROWS / 128), 256, 0, stream>>>(cb, wt3, (float*)d_out);
}

// Round 4
// 257.977 us; speedup vs baseline: 9.0176x; 1.2882x over previous
//
#include <hip/hip_runtime.h>

#define S_LEN 2048
#define D_DIM 1024
#define NH    16
#define HD    64
#define BATCH 4
#define M_ROWS 8192

typedef __attribute__((ext_vector_type(8))) short bf16x8;   // 8 bf16 = 4 VGPR
typedef __attribute__((ext_vector_type(4))) float f32x4;
typedef __attribute__((ext_vector_type(8))) unsigned short u16x8;

__device__ __forceinline__ unsigned short f2bf(float f) {
    unsigned u = __builtin_bit_cast(unsigned, f);
    u = (u + 0x7fffu + ((u >> 16) & 1u)) >> 16;   // RNE
    return (unsigned short)u;
}
// round-half-up pack of two f32 -> packed bf16x2 (bias cancels: l from same P)
__device__ __forceinline__ unsigned pack2(float a, float b) {
    unsigned ua = __builtin_bit_cast(unsigned, a);
    unsigned ub = __builtin_bit_cast(unsigned, b);
    return ((ua + 0x8000u) >> 16) | ((ub + 0x8000u) & 0xffff0000u);
}

__device__ __forceinline__ void gload16(const void* g, void* l) {
    __builtin_amdgcn_global_load_lds((const __attribute__((address_space(1))) unsigned*)g,
                                     (__attribute__((address_space(3))) unsigned*)l,
                                     16, 0, 0);
}

// ---------------------------------------------------------------------------
// x fp32 -> bf16
// ---------------------------------------------------------------------------
__global__ __launch_bounds__(256) void castx_k(const float* __restrict__ x,
                                               unsigned short* __restrict__ o) {
    size_t i = (size_t)blockIdx.x * 256 + threadIdx.x;
    const float4* xf = (const float4*)x;
    float4 a = xf[2 * i], b = xf[2 * i + 1];
    u16x8 v;
    v[0] = f2bf(a.x); v[1] = f2bf(a.y); v[2] = f2bf(a.z); v[3] = f2bf(a.w);
    v[4] = f2bf(b.x); v[5] = f2bf(b.y); v[6] = f2bf(b.z); v[7] = f2bf(b.w);
    *(u16x8*)(o + i * 8) = v;
}

// ---------------------------------------------------------------------------
// W fp32 [K][N] -> bf16 transposed [N][K]; wq pre-scaled by 0.125*log2(e).
// ---------------------------------------------------------------------------
__global__ __launch_bounds__(256) void wprep_k(const float* __restrict__ w0, const float* __restrict__ w1,
                                               const float* __restrict__ w2, const float* __restrict__ w3,
                                               unsigned short* __restrict__ o0, unsigned short* __restrict__ o1,
                                               unsigned short* __restrict__ o2, unsigned short* __restrict__ o3) {
    __shared__ float sT[64][65];
    const float* w; unsigned short* o;
    switch (blockIdx.z) {
        case 0: w = w0; o = o0; break;
        case 1: w = w1; o = o1; break;
        case 2: w = w2; o = o2; break;
        default: w = w3; o = o3; break;
    }
    const float sc = (blockIdx.z == 0) ? 0.18033688011112042f : 1.0f;
    const int t = threadIdx.x;
    const int k0 = blockIdx.y * 64, n0 = blockIdx.x * 64;
    const int r = t >> 4, cq = t & 15;
#pragma unroll
    for (int it = 0; it < 4; ++it) {
        int k = r + it * 16;
        float4 v = *(const float4*)&w[(size_t)(k0 + k) * D_DIM + n0 + cq * 4];
        sT[k][cq * 4 + 0] = v.x; sT[k][cq * 4 + 1] = v.y;
        sT[k][cq * 4 + 2] = v.z; sT[k][cq * 4 + 3] = v.w;
    }
    __syncthreads();
    const int n = t >> 2, ch = t & 3;
    union { unsigned short s[8]; uint4 v; } p0, p1;
#pragma unroll
    for (int j = 0; j < 8; ++j) p0.s[j] = f2bf(sT[ch * 16 + j][n] * sc);
#pragma unroll
    for (int j = 0; j < 8; ++j) p1.s[j] = f2bf(sT[ch * 16 + 8 + j][n] * sc);
    *(uint4*)&o[(size_t)(n0 + n) * D_DIM + k0 + ch * 16]     = p0.v;
    *(uint4*)&o[(size_t)(n0 + n) * D_DIM + k0 + ch * 16 + 8] = p1.v;
}

// ---------------------------------------------------------------------------
// Fused QKV GEMM: C = x(8192x1024) * [WqT|WkT|WvT]^T, bf16 out, m97 structure.
// ---------------------------------------------------------------------------
__global__ __launch_bounds__(256) void gemmqkv_k(const unsigned short* __restrict__ A,
                                                 const unsigned short* __restrict__ Bt,
                                                 unsigned short* __restrict__ qkv)
{
    __shared__ unsigned short sA[128 * 32];
    __shared__ unsigned short sB[128 * 32];
    const int t = threadIdx.x;
    const int lane = t & 63, w = t >> 6;
    const int mm = lane & 15, quad = lane >> 4;
    const int wm = w >> 1, wn = w & 1;
    const int m0 = blockIdx.y * 128, n0 = blockIdx.x * 128;

    f32x4 acc[4][4];
#pragma unroll
    for (int i = 0; i < 4; ++i)
#pragma unroll
        for (int j = 0; j < 4; ++j) acc[i][j] = (f32x4){0.f, 0.f, 0.f, 0.f};

    for (int k0 = 0; k0 < D_DIM; k0 += 32) {
        __syncthreads();
#pragma unroll
        for (int it = 0; it < 2; ++it) {
            int idx = t + it * 256;
            int m = idx >> 2, j = idx & 3;
            int g = (j - (m >> 1)) & 3;
            gload16(A  + ((size_t)(m0 + m) * D_DIM + k0 + g * 8), (void*)&sA[idx * 8]);
            gload16(Bt + ((size_t)(n0 + m) * D_DIM + k0 + g * 8), (void*)&sB[idx * 8]);
        }
        __syncthreads();

        bf16x8 af[4], bfr[4];
#pragma unroll
        for (int mi = 0; mi < 4; ++mi) {
            int m = wm * 64 + mi * 16 + mm;
            int slot = (quad + (m >> 1)) & 3;
            af[mi] = *(const bf16x8*)&sA[m * 32 + slot * 8];
        }
#pragma unroll
        for (int ni = 0; ni < 4; ++ni) {
            int n = wn * 64 + ni * 16 + mm;
            int slot = (quad + (n >> 1)) & 3;
            bfr[ni] = *(const bf16x8*)&sB[n * 32 + slot * 8];
        }
#pragma unroll
        for (int mi = 0; mi < 4; ++mi)
#pragma unroll
            for (int ni = 0; ni < 4; ++ni)
                acc[mi][ni] = __builtin_amdgcn_mfma_f32_16x16x32_bf16(af[mi], bfr[ni], acc[mi][ni], 0, 0, 0);
    }

    const int widx = n0 >> 10;
    const int nl0  = n0 & 1023;
    unsigned short* outp = qkv + (size_t)widx * ((size_t)M_ROWS * D_DIM);
#pragma unroll
    for (int mi = 0; mi < 4; ++mi)
#pragma unroll
        for (int ni = 0; ni < 4; ++ni)
#pragma unroll
            for (int r = 0; r < 4; ++r)
                outp[(size_t)(m0 + wm * 64 + mi * 16 + quad * 4 + r) * D_DIM +
                     nl0 + wn * 64 + ni * 16 + mm] = f2bf(acc[mi][ni][r]);
}

// ---------------------------------------------------------------------------
// Output GEMM: out_fp32 = ctx_bf16 * WoT^T
// ---------------------------------------------------------------------------
__global__ __launch_bounds__(256) void gemmo_k(const unsigned short* __restrict__ A,
                                               const unsigned short* __restrict__ Bt,
                                               float* __restrict__ C)
{
    __shared__ unsigned short sA[128 * 32];
    __shared__ unsigned short sB[128 * 32];
    const int t = threadIdx.x;
    const int lane = t & 63, w = t >> 6;
    const int mm = lane & 15, quad = lane >> 4;
    const int wm = w >> 1, wn = w & 1;
    const int m0 = blockIdx.y * 128, n0 = blockIdx.x * 128;

    f32x4 acc[4][4];
#pragma unroll
    for (int i = 0; i < 4; ++i)
#pragma unroll
        for (int j = 0; j < 4; ++j) acc[i][j] = (f32x4){0.f, 0.f, 0.f, 0.f};

    for (int k0 = 0; k0 < D_DIM; k0 += 32) {
        __syncthreads();
#pragma unroll
        for (int it = 0; it < 2; ++it) {
            int idx = t + it * 256;
            int m = idx >> 2, j = idx & 3;
            int g = (j - (m >> 1)) & 3;
            gload16(A  + ((size_t)(m0 + m) * D_DIM + k0 + g * 8), (void*)&sA[idx * 8]);
            gload16(Bt + ((size_t)(n0 + m) * D_DIM + k0 + g * 8), (void*)&sB[idx * 8]);
        }
        __syncthreads();

        bf16x8 af[4], bfr[4];
#pragma unroll
        for (int mi = 0; mi < 4; ++mi) {
            int m = wm * 64 + mi * 16 + mm;
            int slot = (quad + (m >> 1)) & 3;
            af[mi] = *(const bf16x8*)&sA[m * 32 + slot * 8];
        }
#pragma unroll
        for (int ni = 0; ni < 4; ++ni) {
            int n = wn * 64 + ni * 16 + mm;
            int slot = (quad + (n >> 1)) & 3;
            bfr[ni] = *(const bf16x8*)&sB[n * 32 + slot * 8];
        }
#pragma unroll
        for (int mi = 0; mi < 4; ++mi)
#pragma unroll
            for (int ni = 0; ni < 4; ++ni)
                acc[mi][ni] = __builtin_amdgcn_mfma_f32_16x16x32_bf16(af[mi], bfr[ni], acc[mi][ni], 0, 0, 0);
    }
#pragma unroll
    for (int mi = 0; mi < 4; ++mi)
#pragma unroll
        for (int ni = 0; ni < 4; ++ni)
#pragma unroll
            for (int r = 0; r < 4; ++r)
                C[(size_t)(m0 + wm * 64 + mi * 16 + quad * 4 + r) * D_DIM +
                  n0 + wn * 64 + ni * 16 + mm] = acc[mi][ni][r];
}

// ---------------------------------------------------------------------------
// V row-major [8192][1024] -> V^T per head: vt[bh][hd][s]
// ---------------------------------------------------------------------------
__global__ __launch_bounds__(256) void vtrans_k(const unsigned short* __restrict__ vb,
                                                unsigned short* __restrict__ vt)
{
    __shared__ unsigned short sT[64][72];
    const int t = threadIdx.x;
    const int st0 = blockIdx.x * 64, bh = blockIdx.y;
    const int b = bh >> 4, hh = bh & 15;
#pragma unroll
    for (int it = 0; it < 2; ++it) {
        int idx = t + it * 256;
        int r = idx >> 3, j = idx & 7;
        u16x8 v = *(const u16x8*)&vb[(size_t)(b * S_LEN + st0 + r) * D_DIM + hh * 64 + j * 8];
#pragma unroll
        for (int e = 0; e < 8; ++e) sT[j * 8 + e][r] = v[e];
    }
    __syncthreads();
#pragma unroll
    for (int it = 0; it < 2; ++it) {
        int idx = t + it * 256;
        int hd = idx >> 3, j = idx & 7;
        u16x8 ov = *(const u16x8*)&sT[hd][j * 8];
        *(u16x8*)&vt[((size_t)bh * HD + hd) * S_LEN + st0 + j * 8] = ov;
    }
}

// ---------------------------------------------------------------------------
// Fused causal flash attention, bf16 MFMA, fixed-max softmax.
// 512 threads (8 waves), 16 q-rows/wave, block covers strips {qt, 15-qt}
// (uniform 34 k-tiles). K/V^T double-buffered in LDS with prefetch issued
// AFTER the per-tile barrier -> the vmcnt drain at each barrier waits on
// loads issued a full compute phase earlier (hides global latency).
// l computed via MFMA against all-ones B; sP rows are wave-private.
// ---------------------------------------------------------------------------
__global__ __launch_bounds__(512, 4) void attn_k(const unsigned short* __restrict__ Q,
                                                 const unsigned short* __restrict__ K,
                                                 const unsigned short* __restrict__ Vt,
                                                 unsigned short* __restrict__ ctx)
{
    __shared__ unsigned short sK [2][64 * 64];   // [buf][key][hd]   2x8KB
    __shared__ unsigned short sVT[2][64 * 64];   // [buf][hd][key]   2x8KB
    __shared__ unsigned short sP [128 * 64];     // [qrow][key]      16KB
    const int t = threadIdx.x;
    const int lane = t & 63, w = t >> 6;          // w = 0..7
    const int mm = lane & 15, quad = lane >> 4;
    const int pair = blockIdx.x, bh = blockIdx.y;
    const int b = bh >> 4, hh = bh & 15;
    const size_t rowbase = (size_t)b * S_LEN;
    const int coff = hh * HD;
    const unsigned short* Vh = Vt + (size_t)bh * HD * S_LEN;

    // staging geometry: 512 lanes cover one 64x128B tile per buffer
    const int sc_ = t >> 3, sj = t & 7, sg = sj ^ (sc_ & 7);

    u16x8 onesu;
#pragma unroll
    for (int j = 0; j < 8; ++j) onesu[j] = 0x3F80;   // bf16 1.0
    const bf16x8 ones = __builtin_bit_cast(bf16x8, onesu);

    for (int sidx = 0; sidx < 2; ++sidx) {
        const int qt = sidx ? (15 - pair) : pair;
        const int q0 = qt * 128;

        bf16x8 qf[2];
#pragma unroll
        for (int kk = 0; kk < 2; ++kk)
            qf[kk] = *(const bf16x8*)(Q + (rowbase + q0 + w * 16 + mm) * D_DIM
                                        + coff + kk * 32 + quad * 8);
        f32x4 o[4], lacc;
        lacc = (f32x4){0.f, 0.f, 0.f, 0.f};
#pragma unroll
        for (int hf = 0; hf < 4; ++hf) o[hf] = (f32x4){0.f, 0.f, 0.f, 0.f};

        const int nkt = 2 * qt + 2;
        const int qr = q0 + w * 16 + mm;          // this lane's q-row
        const int qrmax = q0 + w * 16 + 15;       // wave's max q-row

        // prologue: stage tile 0 into buf 0
        gload16(K  + (rowbase + sc_) * D_DIM + coff + sg * 8, (void*)&sK[0][t * 8]);
        gload16(Vh + (size_t)sc_ * S_LEN + sg * 8,            (void*)&sVT[0][t * 8]);

        for (int kt = 0; kt < nkt; ++kt) {
            const int buf = kt & 1;
            __syncthreads();   // buf's loads drained (issued a full phase ago)
            if (kt + 1 < nkt) {
                const int k1 = (kt + 1) * 64;
                gload16(K  + (rowbase + k1 + sc_) * D_DIM + coff + sg * 8,
                        (void*)&sK[1 - buf][t * 8]);
                gload16(Vh + (size_t)sc_ * S_LEN + k1 + sg * 8,
                        (void*)&sVT[1 - buf][t * 8]);
            }
            const int k0 = kt * 64;
            if (k0 > qrmax) continue;   // fully masked for this wave

            // S^T = K Q^T : A = K rows, B = Q rows
            f32x4 sacc[4];
#pragma unroll
            for (int kf = 0; kf < 4; ++kf) sacc[kf] = (f32x4){0.f, 0.f, 0.f, 0.f};
#pragma unroll
            for (int kk = 0; kk < 2; ++kk) {
                bf16x8 ak[4];
#pragma unroll
                for (int kf = 0; kf < 4; ++kf) {
                    int key = kf * 16 + mm;
                    int slot = (kk * 4 + quad) ^ (key & 7);
                    ak[kf] = *(const bf16x8*)&sK[buf][key * 64 + slot * 8];
                }
#pragma unroll
                for (int kf = 0; kf < 4; ++kf)
                    sacc[kf] = __builtin_amdgcn_mfma_f32_16x16x32_bf16(ak[kf], qf[kk], sacc[kf], 0, 0, 0);
            }

            // p = exp2(s), causal mask -> 0, pack to wave-private sP rows
            const bool needmask = (k0 + 63) > (q0 + w * 16);
            const int m = w * 16 + mm;
#pragma unroll
            for (int kf = 0; kf < 4; ++kf) {
                float p[4];
#pragma unroll
                for (int r = 0; r < 4; ++r) {
                    p[r] = __builtin_amdgcn_exp2f(sacc[kf][r]);
                    if (needmask && (k0 + kf * 16 + quad * 4 + r) > qr) p[r] = 0.f;
                }
                unsigned lo = pack2(p[0], p[1]), hi = pack2(p[2], p[3]);
                int slot = (kf * 2 + (quad >> 1)) ^ (m & 7);
                *(unsigned long long*)&sP[m * 64 + slot * 8 + (quad & 1) * 4] =
                    ((unsigned long long)hi << 32) | lo;
            }

            // O += P V ; l += P * ones
#pragma unroll
            for (int kk = 0; kk < 2; ++kk) {
                bf16x8 pf, vf[4];
                {
                    int slot = (kk * 4 + quad) ^ (m & 7);
                    pf = *(const bf16x8*)&sP[m * 64 + slot * 8];
                }
#pragma unroll
                for (int hf = 0; hf < 4; ++hf) {
                    int hd = hf * 16 + mm;
                    int slot = (kk * 4 + quad) ^ (hd & 7);
                    vf[hf] = *(const bf16x8*)&sVT[buf][hd * 64 + slot * 8];
                }
                lacc = __builtin_amdgcn_mfma_f32_16x16x32_bf16(pf, ones, lacc, 0, 0, 0);
#pragma unroll
                for (int hf = 0; hf < 4; ++hf)
                    o[hf] = __builtin_amdgcn_mfma_f32_16x16x32_bf16(pf, vf[hf], o[hf], 0, 0, 0);
            }
        }
        __syncthreads();   // all compute done before next strip's prologue restages buf0

        // normalize (l already in C-layout) and store ctx
#pragma unroll
        for (int r = 0; r < 4; ++r) {
            float inv = 1.f / lacc[r];
            int row = q0 + w * 16 + quad * 4 + r;
#pragma unroll
            for (int hf = 0; hf < 4; ++hf)
                ctx[(rowbase + row) * D_DIM + coff + hf * 16 + mm] = f2bf(o[hf][r] * inv);
        }
    }
}

extern "C" void kernel_launch(void* const* d_in, const int* in_sizes, int n_in,
                              void* d_out, int out_size, void* d_ws, size_t ws_size,
                              hipStream_t stream)
{
    const float* x  = (const float*)d_in[0];
    const float* wq = (const float*)d_in[1];
    const float* wk = (const float*)d_in[2];
    const float* wv = (const float*)d_in[3];
    const float* wo = (const float*)d_in[4];

    const size_t XE = (size_t)M_ROWS * D_DIM;   // 8M elems
    const size_t WE = (size_t)D_DIM * D_DIM;    // 1M elems
    unsigned short* ws  = (unsigned short*)d_ws;
    unsigned short* xbf = ws;
    unsigned short* wt0 = xbf + XE;
    unsigned short* wt1 = wt0 + WE;
    unsigned short* wt2 = wt1 + WE;
    unsigned short* wt3 = wt2 + WE;
    unsigned short* qb  = wt3 + WE;     // q,k,v contiguous (fused epilogue)
    unsigned short* kb  = qb + XE;
    unsigned short* vb  = kb + XE;
    unsigned short* vt  = vb + XE;
    unsigned short* cb  = vt + XE;

    castx_k<<<dim3(M_ROWS * D_DIM / (256 * 8)), 256, 0, stream>>>(x, xbf);
    wprep_k<<<dim3(16, 16, 4), 256, 0, stream>>>(wq, wk, wv, wo, wt0, wt1, wt2, wt3);

    gemmqkv_k<<<dim3(3 * D_DIM / 128, M_ROWS / 128), 256, 0, stream>>>(xbf, wt0, qb);
    vtrans_k<<<dim3(S_LEN / 64, BATCH * NH), 256, 0, stream>>>(vb, vt);

    attn_k<<<dim3(8, BATCH * NH), 512, 0, stream>>>(qb, kb, vt, cb);

    gemmo_k<<<dim3(D_DIM / 128, M_ROWS / 128), 256, 0, stream>>>(cb, wt3, (float*)d_out);
}